// Round 11
// baseline (208.499 us; speedup 1.0000x reference)
//
#include <hip/hip_runtime.h>
#include <math.h>

#define N_EMB 1024
#define D_EMB 512
#define LN_N  6.9314718056f   // ln(1024)
#define ROWS_PER_WAVE 4

typedef float f32x4 __attribute__((ext_vector_type(4)));

__device__ __forceinline__ void load_row(const float* __restrict__ base,
                                         int lane, f32x4 dst[4]) {
    const f32x4* p = (const f32x4*)base;
    #pragma unroll
    for (int c = 0; c < 4; ++c) dst[c] = p[c * 64 + lane];
}

// Full per-row pipeline stage: argmax(l+g), softmax denom, diff write, zq gather.
__device__ __forceinline__ void process_row(
    int row, int lane,
    const f32x4 l4[4], const f32x4 u4[4],
    const float* __restrict__ embed,
    float* __restrict__ zq, float* __restrict__ diff,
    float* __restrict__ indf)
{
    const size_t rbase = (size_t)row * N_EMB;

    // ---- gumbel-perturbed argmax (libm logf: argmax-critical) + logit max ----
    float smax = -INFINITY; int sidx = 0;
    float lmax = -INFINITY;
    #pragma unroll
    for (int c = 0; c < 4; ++c) {
        #pragma unroll
        for (int j = 0; j < 4; ++j) {
            const float lvx = l4[c][j];
            const float g   = -logf(-logf(u4[c][j]));   // gumbel noise
            const float sc  = lvx + g;                  // tau == 1.0
            const int idx   = c * 256 + lane * 4 + j;
            if (sc > smax) { smax = sc; sidx = idx; }   // first-idx ties
            lmax = fmaxf(lmax, lvx);
        }
    }

    // ---- wave butterfly: argmax(score) + max(logit) ----
    #pragma unroll
    for (int off = 32; off > 0; off >>= 1) {
        const float v2 = __shfl_xor(smax, off, 64);
        const int   i2 = __shfl_xor(sidx, off, 64);
        if (v2 > smax || (v2 == smax && i2 < sidx)) { smax = v2; sidx = i2; }
        lmax = fmaxf(lmax, __shfl_xor(lmax, off, 64));
    }
    const int   ind = sidx;
    const float m   = lmax;

    // ---- softmax denominator (hw exp) ----
    float psum = 0.f;
    #pragma unroll
    for (int c = 0; c < 4; ++c)
        #pragma unroll
        for (int j = 0; j < 4; ++j) psum += __expf(l4[c][j] - m);
    #pragma unroll
    for (int off = 32; off > 0; off >>= 1) psum += __shfl_xor(psum, off, 64);
    const float sum = psum;                  // same on all lanes
    const float L   = LN_N - logf(sum);      // ln(N/sum), once per row

    // ---- diff = -ln(qy*N)/qy = -((lv-m)+L) * sum * exp(m-lv) ----
    f32x4* dp = (f32x4*)(diff + rbase);
    #pragma unroll
    for (int c = 0; c < 4; ++c) {
        f32x4 d;
        #pragma unroll
        for (int j = 0; j < 4; ++j) {
            const float lvx = l4[c][j];
            d[j] = -((lvx - m) + L) * sum * __expf(m - lvx);
        }
        __builtin_nontemporal_store(d, dp + c * 64 + lane);
    }

    // ---- z_q row = embed[ind] (2 KB gather, L2-hot) ----
    const f32x4* erow = (const f32x4*)(embed + (size_t)ind * D_EMB);
    f32x4*       zrow = (f32x4*)(zq + (size_t)row * D_EMB);
    #pragma unroll
    for (int c = 0; c < 2; ++c)
        __builtin_nontemporal_store(erow[c * 64 + lane], zrow + c * 64 + lane);

    if (lane == 0) __builtin_nontemporal_store((float)ind, indf + row);
}

// Persistent pipelined waves: each wave owns ROWS_PER_WAVE rows (stride =
// waves_total) with a register double-buffer. Steady state interleaves the
// NEXT row's 8 KB loads with the CURRENT row's compute + 6 KB stores, so
// read and write demand overlap continuously (like the 6.3 TB/s copy bench)
// instead of the read-burst/write-burst phases of previous rounds.
__global__ __launch_bounds__(256) void gumbel_quantize_kernel(
    const float* __restrict__ logits,   // [rows, 1024]
    const float* __restrict__ u,        // [rows, 1024]
    const float* __restrict__ embed,    // [1024, 512]
    float*       __restrict__ zq,       // [rows, 512]
    float*       __restrict__ diff,     // [rows, 1024]
    float*       __restrict__ indf,     // [rows]
    int waves_total)                    // rows / ROWS_PER_WAVE
{
    const int lane = threadIdx.x & 63;
    const int wave = threadIdx.x >> 6;
    const int wid  = blockIdx.x * 4 + wave;

    f32x4 lA[4], uA[4], lB[4], uB[4];

    const int r0 = wid;
    const int r1 = wid + waves_total;
    const int r2 = wid + 2 * waves_total;
    const int r3 = wid + 3 * waves_total;

    // prologue: fill buffer A with row 0
    load_row(logits + (size_t)r0 * N_EMB, lane, lA);
    load_row(u      + (size_t)r0 * N_EMB, lane, uA);

    // t=0: prefetch row1 -> B, process row0 from A
    load_row(logits + (size_t)r1 * N_EMB, lane, lB);
    load_row(u      + (size_t)r1 * N_EMB, lane, uB);
    process_row(r0, lane, lA, uA, embed, zq, diff, indf);

    // t=1: prefetch row2 -> A, process row1 from B
    load_row(logits + (size_t)r2 * N_EMB, lane, lA);
    load_row(u      + (size_t)r2 * N_EMB, lane, uA);
    process_row(r1, lane, lB, uB, embed, zq, diff, indf);

    // t=2: prefetch row3 -> B, process row2 from A
    load_row(logits + (size_t)r3 * N_EMB, lane, lB);
    load_row(u      + (size_t)r3 * N_EMB, lane, uB);
    process_row(r2, lane, lA, uA, embed, zq, diff, indf);

    // t=3: process row3 from B (no prefetch)
    process_row(r3, lane, lB, uB, embed, zq, diff, indf);
}

extern "C" void kernel_launch(void* const* d_in, const int* in_sizes, int n_in,
                              void* d_out, int out_size, void* d_ws, size_t ws_size,
                              hipStream_t stream) {
    const float* logits = (const float*)d_in[0];
    const float* u      = (const float*)d_in[1];
    const float* embed  = (const float*)d_in[2];

    const int rows = in_sizes[0] / N_EMB;   // 8*2048 = 16384

    float* out  = (float*)d_out;
    float* zq   = out;                                   // rows*512
    float* diff = zq + (size_t)rows * D_EMB;             // rows*1024
    float* indf = diff + (size_t)rows * N_EMB;           // rows

    const int waves_total = rows / ROWS_PER_WAVE;        // 4096 waves
    const int blocks      = waves_total / 4;             // 1024 blocks (4/CU)

    gumbel_quantize_kernel<<<blocks, 256, 0, stream>>>(logits, u, embed,
                                                       zq, diff, indf,
                                                       waves_total);
}